// Round 19
// baseline (61.209 us; speedup 1.0000x reference)
//
#include <hip/hip_runtime.h>
#include <hip/hip_bf16.h>

#define HDIM 768
#define NSUP 128
#define NTOT 384
#define NREL 8
#define WPLANE (HDIM*HDIM)
#define W1LD  (2*HDIM)

typedef unsigned short u16;
typedef __attribute__((ext_vector_type(8))) short bf16x8;
typedef __attribute__((ext_vector_type(4))) float f32x4;
typedef _Float16 h2v __attribute__((ext_vector_type(2)));

// fragment-tiled staging: [tile][kchunk(24)][frag(2)][lane(64)][elem(8)]
#define EMB_SLOTS   36864
#define W_SLOTS     73728
#define TILES_SLOTS (EMB_SLOTS + 5*W_SLOTS)   // 405504

__device__ __forceinline__ u16 f2b(float f){
  unsigned x = __float_as_uint(f);
  return (u16)((x + 0x7fffu + ((x>>16)&1u)) >> 16);
}
__device__ __forceinline__ float b2f(u16 u){ return __uint_as_float(((unsigned)u)<<16); }
__device__ __forceinline__ u16 f2h_bits(float f){
  _Float16 h = (_Float16)f;
  return __builtin_bit_cast(unsigned short, h);
}

__device__ __forceinline__ const float* emb_row(const float* sup, const float* qry, int row){
  return row < NSUP ? sup + (size_t)row*HDIM : qry + (size_t)(row-NSUP)*HDIM;
}

// pair swizzled R layout: elem (m=j, n=k) -> group (j>>3) of 6144 f16;
// slot = (c*64 + s*8 + (j&7)) uint4s, c=(n%96)>>3, s=n/96, elem n&7
__device__ __forceinline__ size_t rswz(int m, int n){
  int s = n / 96;
  int c = (n % 96) >> 3;
  return (size_t)(m >> 3)*6144 + (size_t)((c*64 + s*8 + (m & 7))*8 + (n & 7));
}

// ---------------- prep2_k: fragment tiles (bf16) + bsum (f32) + w2h (f16) ----------------
__global__ __launch_bounds__(256) void prep2_k(
    const float* __restrict__ sup, const float* __restrict__ qry,
    const float* __restrict__ relW, const float* __restrict__ relB,
    const float* __restrict__ simW1, const float* __restrict__ divW1,
    const float* __restrict__ simw2, const float* __restrict__ divw2,
    u16* __restrict__ tiles, float* __restrict__ bsum, u16* __restrict__ w2h){
  int s = blockIdx.x*256 + threadIdx.x;
  if (s < TILES_SLOTS){
    int lane = s & 63, f = (s>>6) & 1;
    int seg, loc;
    if (s < EMB_SLOTS){ seg = 0; loc = s; }
    else { int ls = s - EMB_SLOTS; seg = 1 + ls / W_SLOTS; loc = ls % W_SLOTS; }
    int lt2 = loc >> 7;
    int kc = lt2 % 24, tile = lt2 / 24;
    int row = tile*32 + f*16 + (lane & 15);
    int ksrc = kc*32 + (lane>>4)*8;
    float v[8];
    if (seg == 0){
      const float* src = emb_row(sup, qry, row) + ksrc;
      float4 a = *reinterpret_cast<const float4*>(src);
      float4 b = *reinterpret_cast<const float4*>(src + 4);
      v[0]=a.x; v[1]=a.y; v[2]=a.z; v[3]=a.w; v[4]=b.x; v[5]=b.y; v[6]=b.z; v[7]=b.w;
    } else if (seg <= 4){
      const float* base = (seg <= 2) ? simW1 : divW1;
      int koff = ((seg-1) & 1) ? HDIM : 0;
      const float* src = base + (size_t)row*W1LD + koff + ksrc;
      float4 a = *reinterpret_cast<const float4*>(src);
      float4 b = *reinterpret_cast<const float4*>(src + 4);
      v[0]=a.x; v[1]=a.y; v[2]=a.z; v[3]=a.w; v[4]=b.x; v[5]=b.y; v[6]=b.z; v[7]=b.w;
    } else {
      const float* src = relW + (size_t)row*HDIM + ksrc;
#pragma unroll
      for (int e=0;e<8;e++) v[e] = 0.f;
#pragma unroll
      for (int r=0;r<NREL;r++){
        float4 a = *reinterpret_cast<const float4*>(src + (size_t)r*WPLANE);
        float4 b = *reinterpret_cast<const float4*>(src + (size_t)r*WPLANE + 4);
        v[0]+=a.x; v[1]+=a.y; v[2]+=a.z; v[3]+=a.w; v[4]+=b.x; v[5]+=b.y; v[6]+=b.z; v[7]+=b.w;
      }
    }
    u16 o[8];
#pragma unroll
    for (int e=0;e<8;e++) o[e] = f2b(v[e]);
    ushort4* dst = reinterpret_cast<ushort4*>(tiles + (size_t)s*8);
    dst[0] = make_ushort4(o[0],o[1],o[2],o[3]);
    dst[1] = make_ushort4(o[4],o[5],o[6],o[7]);
  }
  if (blockIdx.x == 0 && threadIdx.x < HDIM/4){
    int c = threadIdx.x*4;
    float4 sbv = make_float4(0.f,0.f,0.f,0.f);
#pragma unroll
    for (int r=0;r<NREL;r++){
      float4 vv = *reinterpret_cast<const float4*>(relB + r*HDIM + c);
      sbv.x+=vv.x; sbv.y+=vv.y; sbv.z+=vv.z; sbv.w+=vv.w;
    }
    *reinterpret_cast<float4*>(bsum + c) = sbv;
  }
  if (blockIdx.x == 1){
    for (int e = threadIdx.x; e < 384; e += 256){
      int zz = e / 192, qq = e % 192;
      const float* w2src = zz ? divw2 : simw2;
      float4 wv = reinterpret_cast<const float4*>(w2src)[qq];
      ushort4 o;
      o.x = f2h_bits(wv.x); o.y = f2h_bits(wv.y); o.z = f2h_bits(wv.z); o.w = f2h_bits(wv.w);
      reinterpret_cast<ushort4*>(w2h + zz*HDIM)[qq] = o;
    }
  }
}

// ---------------- gemm5v4_k: coalesced fragment loads; R written in pair swizzle ----------------
struct G5M4 {
  const float* b1f[4];
  u16* outH[4];
  float* outF;
  const float* bsum;
};

__global__ __launch_bounds__(512) void gemm5v4_k(const u16* __restrict__ tiles, G5M4 ga){
  __shared__ f32x4 red[4][4][64];
  int z = blockIdx.z;
  int t = threadIdx.x, lane = t&63, wid = t>>6;
  int q = wid & 3, kh = wid >> 2;
  int mtile = blockIdx.y*2 + (q&1);
  int ntile = blockIdx.x*2 + (q>>1);
  const u16* Ab = tiles + ((size_t)(mtile*24 + kh*12)*2*64 + lane)*8;
  const u16* Bb = tiles + (size_t)(EMB_SLOTS + z*W_SLOTS)*8
                        + ((size_t)(ntile*24 + kh*12)*2*64 + lane)*8;
  f32x4 acc00={0,0,0,0}, acc01={0,0,0,0}, acc10={0,0,0,0}, acc11={0,0,0,0};
  bf16x8 a0 = *reinterpret_cast<const bf16x8*>(Ab);
  bf16x8 a1 = *reinterpret_cast<const bf16x8*>(Ab + 512);
  bf16x8 b0 = *reinterpret_cast<const bf16x8*>(Bb);
  bf16x8 b1 = *reinterpret_cast<const bf16x8*>(Bb + 512);
#pragma unroll
  for (int c=0;c<12;c++){
    bf16x8 na0, na1, nb0, nb1;
    if (c < 11){
      na0 = *reinterpret_cast<const bf16x8*>(Ab + (c+1)*1024);
      na1 = *reinterpret_cast<const bf16x8*>(Ab + (c+1)*1024 + 512);
      nb0 = *reinterpret_cast<const bf16x8*>(Bb + (c+1)*1024);
      nb1 = *reinterpret_cast<const bf16x8*>(Bb + (c+1)*1024 + 512);
    }
    acc00 = __builtin_amdgcn_mfma_f32_16x16x32_bf16(a0, b0, acc00, 0, 0, 0);
    acc10 = __builtin_amdgcn_mfma_f32_16x16x32_bf16(a1, b0, acc10, 0, 0, 0);
    acc01 = __builtin_amdgcn_mfma_f32_16x16x32_bf16(a0, b1, acc01, 0, 0, 0);
    acc11 = __builtin_amdgcn_mfma_f32_16x16x32_bf16(a1, b1, acc11, 0, 0, 0);
    a0 = na0; a1 = na1; b0 = nb0; b1 = nb1;
  }
  if (kh){
    red[q][0][lane] = acc00;
    red[q][1][lane] = acc01;
    red[q][2][lane] = acc10;
    red[q][3][lane] = acc11;
  }
  __syncthreads();
  if (!kh){
    acc00 += red[q][0][lane];
    acc01 += red[q][1][lane];
    acc10 += red[q][2][lane];
    acc11 += red[q][3][lane];
    int l15 = lane & 15;
    int r0 = (lane>>4)*4;
    int m0 = mtile*32, n0 = ntile*32;
    if (z < 4){
      u16* outp = ga.outH[z];
      if ((z & 1) == 0){
        const float* b1f = ga.b1f[z];
        float bn0 = b1f[n0 + l15];
        float bn1 = b1f[n0 + 16 + l15];
#pragma unroll
        for (int r=0;r<4;r++){
          outp[(size_t)(m0 + r0 + r)*HDIM      + n0 + l15]      = f2h_bits(acc00[r] + bn0);
          outp[(size_t)(m0 + r0 + r)*HDIM      + n0 + 16 + l15] = f2h_bits(acc01[r] + bn1);
          outp[(size_t)(m0 + 16 + r0 + r)*HDIM + n0 + l15]      = f2h_bits(acc10[r] + bn0);
          outp[(size_t)(m0 + 16 + r0 + r)*HDIM + n0 + 16 + l15] = f2h_bits(acc11[r] + bn1);
        }
      } else {
#pragma unroll
        for (int r=0;r<4;r++){
          outp[rswz(m0 + r0 + r,      n0 + l15)]      = f2h_bits(acc00[r]);
          outp[rswz(m0 + r0 + r,      n0 + 16 + l15)] = f2h_bits(acc01[r]);
          outp[rswz(m0 + 16 + r0 + r, n0 + l15)]      = f2h_bits(acc10[r]);
          outp[rswz(m0 + 16 + r0 + r, n0 + 16 + l15)] = f2h_bits(acc11[r]);
        }
      }
    } else {
      float* outp = ga.outF;
      float bn0 = ga.bsum[n0 + l15];
      float bn1 = ga.bsum[n0 + 16 + l15];
#pragma unroll
      for (int r=0;r<4;r++){
        outp[(size_t)(m0 + r0 + r)*HDIM      + n0 + l15]      = (acc00[r] + bn0)*0.125f;
        outp[(size_t)(m0 + r0 + r)*HDIM      + n0 + 16 + l15] = (acc01[r] + bn1)*0.125f;
        outp[(size_t)(m0 + 16 + r0 + r)*HDIM + n0 + l15]      = (acc10[r] + bn0)*0.125f;
        outp[(size_t)(m0 + 16 + r0 + r)*HDIM + n0 + 16 + l15] = (acc11[r] + bn1)*0.125f;
      }
    }
  }
}

// ---------------- pair6_k: rolled c-loop (r13 exact), coalesced swizzled R ----------------
struct P6Args {
  const u16* L[2];      // row-major f16 [384][768], b1 folded
  const u16* R[2];      // swizzled f16 (rswz layout)
  const u16* w2h;       // [2][768] f16
  const float* b2[2];
  float* out[2];
};

#define PDOT(LW, RW, WW, ACC) {                                               \
  h2v s_ = __builtin_elementwise_max(                                         \
      __builtin_bit_cast(h2v,(LW)) + __builtin_bit_cast(h2v,(RW)), hz);       \
  ACC = __builtin_amdgcn_fdot2(s_, __builtin_bit_cast(h2v,(WW)), ACC, false); }

__global__ __launch_bounds__(256, 2) void pair6_k(P6Args pa){
  int z = blockIdx.z;
  int i0 = blockIdx.x*8;        // 48 i-blocks
  int jt = blockIdx.y;          // 12 j-tiles (32 j)
  __shared__ u16 Lh[8][768];    // 12KB
  __shared__ u16 w2s[768];      // 1.5KB
  int t = threadIdx.x;
  const u16* __restrict__ L = pa.L[z];
  for (int idx=t; idx<1536; idx+=256){
    int ii = idx/192, qq = idx - ii*192;
    reinterpret_cast<ushort4*>(&Lh[ii][0])[qq] =
        reinterpret_cast<const ushort4*>(L + (size_t)(i0+ii)*HDIM)[qq];
  }
  for (int e=t; e<192; e+=256)
    reinterpret_cast<ushort4*>(w2s)[e] = reinterpret_cast<const ushort4*>(pa.w2h + z*HDIM)[e];
  __syncthreads();
  int w = t>>6, lane = t&63;
  int s = lane>>3, g = lane&7;
  int jb = jt*32 + w*8;
  const h2v hz = {(_Float16)0.f, (_Float16)0.f};
  float acc[8] = {0.f,0.f,0.f,0.f,0.f,0.f,0.f,0.f};

  const u16* rp  = pa.R[z] + (size_t)(jb>>3)*6144 + ((size_t)lane<<3);
  const u16* wp  = &w2s[s*96];
  const u16* lp  = &Lh[0][s*96];
  uint4 rv = *reinterpret_cast<const uint4*>(rp);
#pragma unroll 1
  for (int c=0;c<12;c++){
    uint4 nrv = rv;
    if (c < 11) nrv = *reinterpret_cast<const uint4*>(rp + 512);
    uint4 wv = *reinterpret_cast<const uint4*>(wp);
#pragma unroll
    for (int ii=0;ii<8;ii++){
      uint4 lv = *reinterpret_cast<const uint4*>(lp + ii*768);
      PDOT(lv.x, rv.x, wv.x, acc[ii]);
      PDOT(lv.y, rv.y, wv.y, acc[ii]);
      PDOT(lv.z, rv.z, wv.z, acc[ii]);
      PDOT(lv.w, rv.w, wv.w, acc[ii]);
    }
    rv = nrv; rp += 512; wp += 8; lp += 8;
  }
  float b2v = pa.b2[z][0];
  float* outp = pa.out[z];
#pragma unroll
  for (int ii=0;ii<8;ii++){
    float a = acc[ii];
    a += __shfl_xor(a, 8, 64);
    a += __shfl_xor(a, 16, 64);
    a += __shfl_xor(a, 32, 64);
    if (s == ii){
      int i = i0 + ii, j = jb + g;
      float v = a + b2v;
      if (i == j) v = 0.f;
      outp[(size_t)i*NTOT + j] = v;
    }
  }
}

// ================= fallback (proven zero-ws path) =================
__global__ __launch_bounds__(256) void prop_k(
    const float* __restrict__ sup, const float* __restrict__ qry,
    const float* __restrict__ relW, const float* __restrict__ relB,
    float* __restrict__ outp){
  __shared__ float As[16][68];
  __shared__ float Bs[16][68];
  int t = threadIdx.x;
  int m0 = blockIdx.y*64, n0 = blockIdx.x*64;
  int lm = t>>2, lk = (t&3)<<2;
  int tx = t&15, ty = t>>4;
  float acc[4][4] = {{0,0,0,0},{0,0,0,0},{0,0,0,0},{0,0,0,0}};
  const float* Aptr = emb_row(sup, qry, m0+lm) + lk;
  const float* Bptr = relW + (size_t)(n0+lm)*HDIM + lk;
  for (int k0=0;k0<HDIM;k0+=16){
    float4 av = *reinterpret_cast<const float4*>(Aptr + k0);
    float4 bs = make_float4(0.f,0.f,0.f,0.f);
#pragma unroll
    for (int r=0;r<NREL;r++){
      float4 bv = *reinterpret_cast<const float4*>(Bptr + (size_t)r*WPLANE + k0);
      bs.x += bv.x; bs.y += bv.y; bs.z += bv.z; bs.w += bv.w;
    }
    __syncthreads();
    As[lk+0][lm]=av.x; As[lk+1][lm]=av.y; As[lk+2][lm]=av.z; As[lk+3][lm]=av.w;
    Bs[lk+0][lm]=bs.x; Bs[lk+1][lm]=bs.y; Bs[lk+2][lm]=bs.z; Bs[lk+3][lm]=bs.w;
    __syncthreads();
#pragma unroll
    for (int kk=0;kk<16;kk++){
      float4 a4 = *reinterpret_cast<const float4*>(&As[kk][ty<<2]);
      float4 b4 = *reinterpret_cast<const float4*>(&Bs[kk][tx<<2]);
      float ar[4]={a4.x,a4.y,a4.z,a4.w};
      float br[4]={b4.x,b4.y,b4.z,b4.w};
#pragma unroll
      for (int i2=0;i2<4;i2++)
#pragma unroll
        for (int j2=0;j2<4;j2++)
          acc[i2][j2] = fmaf(ar[i2], br[j2], acc[i2][j2]);
    }
  }
#pragma unroll
  for (int j2=0;j2<4;j2++){
    int n = n0 + (tx<<2) + j2;
    float bias = 0.f;
#pragma unroll
    for (int r=0;r<NREL;r++) bias += relB[r*HDIM + n];
#pragma unroll
    for (int i2=0;i2<4;i2++){
      int m = m0 + (ty<<2) + i2;
      outp[(size_t)m*HDIM + n] = (acc[i2][j2] + bias) * 0.125f;
    }
  }
}

struct NWArgs {
  const float* W1[2]; const float* b1[2]; const float* w2[2]; const float* b2[2];
  float* out[2];
};

__global__ __launch_bounds__(256) void pair_nows_k(
    const float* __restrict__ sup, const float* __restrict__ qry, NWArgs na){
  int z = blockIdx.z, i0 = blockIdx.x*32, j0 = blockIdx.y*32;
  __shared__ u16 Lt[32][768];
  __shared__ float Rj[768];
  __shared__ float b1s[768];
  __shared__ float w2s[768];
  const float* __restrict__ W1 = na.W1[z];
  int t = threadIdx.x;
  for (int k=t;k<768;k+=256){ b1s[k]=na.b1[z][k]; w2s[k]=na.w2[z][k]; }
  for (int e=t; e<32*768; e+=256){
    int ii = e/768, k = e - ii*768;
    const float4* er = reinterpret_cast<const float4*>(emb_row(sup, qry, i0+ii));
    const float4* wr = reinterpret_cast<const float4*>(W1 + (size_t)k*W1LD);
    float s = 0.f;
    for (int h=0;h<192;h++){
      float4 a = er[h], b = wr[h];
      s += a.x*b.x + a.y*b.y + a.z*b.z + a.w*b.w;
    }
    Lt[ii][k] = f2b(s);
  }
  float b2v = na.b2[z][0];
  int w = t>>6, l = t&63;
  float* outp = na.out[z];
  for (int jj=0;jj<32;jj++){
    int j = j0 + jj;
    const float4* ejr = reinterpret_cast<const float4*>(emb_row(sup, qry, j));
    __syncthreads();
    for (int k=t;k<768;k+=256){
      const float4* wr = reinterpret_cast<const float4*>(W1 + (size_t)k*W1LD + HDIM);
      float s = 0.f;
      for (int h=0;h<192;h++){
        float4 a = ejr[h], b = wr[h];
        s += a.x*b.x + a.y*b.y + a.z*b.z + a.w*b.w;
      }
      Rj[k] = s;
    }
    __syncthreads();
    for (int q=0;q<8;q++){
      int ii = (w<<3) + q;
      float acc = 0.f;
#pragma unroll
      for (int u=0;u<12;u++){
        int k = l + (u<<6);
        acc = fmaf(fmaxf(b2f(Lt[ii][k]) + Rj[k] + b1s[k], 0.f), w2s[k], acc);
      }
#pragma unroll
      for (int m=32;m>=1;m>>=1) acc += __shfl_xor(acc, m, 64);
      if (l==0){
        int i = i0 + ii;
        float v = acc + b2v;
        if (i==j) v = 0.f;
        outp[(size_t)i*NTOT + j] = v;
      }
    }
  }
}

extern "C" void kernel_launch(void* const* d_in, const int* in_sizes, int n_in,
                              void* d_out, int out_size, void* d_ws, size_t ws_size,
                              hipStream_t stream) {
  const float* sup   = (const float*)d_in[0];
  // d_in[1] = support_labels (unused)
  const float* qry   = (const float*)d_in[2];
  const float* simW1 = (const float*)d_in[3];
  const float* simb1 = (const float*)d_in[4];
  const float* simw2 = (const float*)d_in[5];
  const float* simb2 = (const float*)d_in[6];
  const float* divW1 = (const float*)d_in[7];
  const float* divb1 = (const float*)d_in[8];
  const float* divw2 = (const float*)d_in[9];
  const float* divb2 = (const float*)d_in[10];
  const float* relW  = (const float*)d_in[11];
  const float* relB  = (const float*)d_in[12];
  float* out = (float*)d_out;
  float* outSim = out + (size_t)NTOT*HDIM;
  float* outDiv = outSim + (size_t)NTOT*NTOT;

  const size_t TILB = (size_t)TILES_SLOTS*8*2;   // 6,488,064 B
  const size_t LRB  = (size_t)NTOT*HDIM*2;       //   589,824 B
  const size_t NEED = TILB + 8192 + 4*LRB;       // ~8.86 MB

  if (ws_size >= NEED){
    char* ws = (char*)d_ws;
    u16*   tiles = (u16*)(ws);
    float* bsum  = (float*)(ws + TILB);
    u16*   w2h   = (u16*)(ws + TILB + 4096);
    u16*   Ls    = (u16*)(ws + TILB + 8192);
    u16*   Rs    = (u16*)((char*)Ls + LRB);
    u16*   Ld    = (u16*)((char*)Rs + LRB);
    u16*   Rd    = (u16*)((char*)Ld + LRB);

    // MEASUREMENT ROUND: prep2 launched 4x (idempotent).
    // o + t_prep = (T - 39.7)/3;  combined with r17's o + t_pair = 16.1.
    prep2_k<<<dim3((TILES_SLOTS + 255)/256), dim3(256), 0, stream>>>(
        sup, qry, relW, relB, simW1, divW1, simw2, divw2, tiles, bsum, w2h);
    prep2_k<<<dim3((TILES_SLOTS + 255)/256), dim3(256), 0, stream>>>(
        sup, qry, relW, relB, simW1, divW1, simw2, divw2, tiles, bsum, w2h);
    prep2_k<<<dim3((TILES_SLOTS + 255)/256), dim3(256), 0, stream>>>(
        sup, qry, relW, relB, simW1, divW1, simw2, divw2, tiles, bsum, w2h);
    prep2_k<<<dim3((TILES_SLOTS + 255)/256), dim3(256), 0, stream>>>(
        sup, qry, relW, relB, simW1, divW1, simw2, divw2, tiles, bsum, w2h);

    G5M4 ga;
    ga.b1f[0]=simb1;   ga.outH[0]=Ls;
    ga.b1f[1]=nullptr; ga.outH[1]=Rs;
    ga.b1f[2]=divb1;   ga.outH[2]=Ld;
    ga.b1f[3]=nullptr; ga.outH[3]=Rd;
    ga.outF=out; ga.bsum=bsum;
    gemm5v4_k<<<dim3(12,6,5), dim3(512), 0, stream>>>(tiles, ga);

    P6Args pa;
    pa.L[0]=Ls; pa.R[0]=Rs; pa.b2[0]=simb2; pa.out[0]=outSim;
    pa.L[1]=Ld; pa.R[1]=Rd; pa.b2[1]=divb2; pa.out[1]=outDiv;
    pa.w2h = w2h;
    pair6_k<<<dim3(48,12,2), dim3(256), 0, stream>>>(pa);
  } else {
    prop_k<<<dim3(12,6), dim3(256), 0, stream>>>(sup, qry, relW, relB, out);
    NWArgs na;
    na.W1[0]=simW1; na.b1[0]=simb1; na.w2[0]=simw2; na.b2[0]=simb2; na.out[0]=outSim;
    na.W1[1]=divW1; na.b1[1]=divb1; na.w2[1]=divw2; na.b2[1]=divb2; na.out[1]=outDiv;
    pair_nows_k<<<dim3(12,12,2), dim3(256), 0, stream>>>(sup, qry, na);
  }
}

// Round 21
// 38.622 us; speedup vs baseline: 1.5848x; 1.5848x over previous
//
#include <hip/hip_runtime.h>
#include <hip/hip_bf16.h>

#define HDIM 768
#define NSUP 128
#define NTOT 384
#define NREL 8
#define WPLANE (HDIM*HDIM)
#define W1LD  (2*HDIM)

typedef unsigned short u16;
typedef __attribute__((ext_vector_type(8))) short bf16x8;
typedef __attribute__((ext_vector_type(4))) float f32x4;
typedef _Float16 h2v __attribute__((ext_vector_type(2)));

// fragment-tiled staging: [tile][kchunk(24)][frag(2)][lane(64)][elem(8)]
#define EMB_SLOTS   36864
#define W_SLOTS     73728
#define TILES_SLOTS (EMB_SLOTS + 5*W_SLOTS)   // 405504

__device__ __forceinline__ u16 f2b(float f){
  unsigned x = __float_as_uint(f);
  return (u16)((x + 0x7fffu + ((x>>16)&1u)) >> 16);
}
__device__ __forceinline__ float b2f(u16 u){ return __uint_as_float(((unsigned)u)<<16); }
__device__ __forceinline__ u16 f2h_bits(float f){
  _Float16 h = (_Float16)f;
  return __builtin_bit_cast(unsigned short, h);
}

__device__ __forceinline__ const float* emb_row(const float* sup, const float* qry, int row){
  return row < NSUP ? sup + (size_t)row*HDIM : qry + (size_t)(row-NSUP)*HDIM;
}

// pair swizzled R layout: elem (m=j, n=k) -> group (j>>3) of 6144 f16;
// slot = (c*64 + s*8 + (j&7)) uint4s, c=(n%96)>>3, s=n/96, elem n&7
__device__ __forceinline__ size_t rswz(int m, int n){
  int s = n / 96;
  int c = (n % 96) >> 3;
  return (size_t)(m >> 3)*6144 + (size_t)((c*64 + s*8 + (m & 7))*8 + (n & 7));
}

// ---------------- prep2_k: fragment tiles (bf16) + bsum (f32) + w2h (f16) ----------------
__global__ __launch_bounds__(256) void prep2_k(
    const float* __restrict__ sup, const float* __restrict__ qry,
    const float* __restrict__ relW, const float* __restrict__ relB,
    const float* __restrict__ simW1, const float* __restrict__ divW1,
    const float* __restrict__ simw2, const float* __restrict__ divw2,
    u16* __restrict__ tiles, float* __restrict__ bsum, u16* __restrict__ w2h){
  int s = blockIdx.x*256 + threadIdx.x;
  if (s < TILES_SLOTS){
    int lane = s & 63, f = (s>>6) & 1;
    int seg, loc;
    if (s < EMB_SLOTS){ seg = 0; loc = s; }
    else { int ls = s - EMB_SLOTS; seg = 1 + ls / W_SLOTS; loc = ls % W_SLOTS; }
    int lt2 = loc >> 7;
    int kc = lt2 % 24, tile = lt2 / 24;
    int row = tile*32 + f*16 + (lane & 15);
    int ksrc = kc*32 + (lane>>4)*8;
    float v[8];
    if (seg == 0){
      const float* src = emb_row(sup, qry, row) + ksrc;
      float4 a = *reinterpret_cast<const float4*>(src);
      float4 b = *reinterpret_cast<const float4*>(src + 4);
      v[0]=a.x; v[1]=a.y; v[2]=a.z; v[3]=a.w; v[4]=b.x; v[5]=b.y; v[6]=b.z; v[7]=b.w;
    } else if (seg <= 4){
      const float* base = (seg <= 2) ? simW1 : divW1;
      int koff = ((seg-1) & 1) ? HDIM : 0;
      const float* src = base + (size_t)row*W1LD + koff + ksrc;
      float4 a = *reinterpret_cast<const float4*>(src);
      float4 b = *reinterpret_cast<const float4*>(src + 4);
      v[0]=a.x; v[1]=a.y; v[2]=a.z; v[3]=a.w; v[4]=b.x; v[5]=b.y; v[6]=b.z; v[7]=b.w;
    } else {
      const float* src = relW + (size_t)row*HDIM + ksrc;
#pragma unroll
      for (int e=0;e<8;e++) v[e] = 0.f;
#pragma unroll
      for (int r=0;r<NREL;r++){
        float4 a = *reinterpret_cast<const float4*>(src + (size_t)r*WPLANE);
        float4 b = *reinterpret_cast<const float4*>(src + (size_t)r*WPLANE + 4);
        v[0]+=a.x; v[1]+=a.y; v[2]+=a.z; v[3]+=a.w; v[4]+=b.x; v[5]+=b.y; v[6]+=b.z; v[7]+=b.w;
      }
    }
    u16 o[8];
#pragma unroll
    for (int e=0;e<8;e++) o[e] = f2b(v[e]);
    ushort4* dst = reinterpret_cast<ushort4*>(tiles + (size_t)s*8);
    dst[0] = make_ushort4(o[0],o[1],o[2],o[3]);
    dst[1] = make_ushort4(o[4],o[5],o[6],o[7]);
  }
  if (blockIdx.x == 0 && threadIdx.x < HDIM/4){
    int c = threadIdx.x*4;
    float4 sbv = make_float4(0.f,0.f,0.f,0.f);
#pragma unroll
    for (int r=0;r<NREL;r++){
      float4 vv = *reinterpret_cast<const float4*>(relB + r*HDIM + c);
      sbv.x+=vv.x; sbv.y+=vv.y; sbv.z+=vv.z; sbv.w+=vv.w;
    }
    *reinterpret_cast<float4*>(bsum + c) = sbv;
  }
  if (blockIdx.x == 1){
    for (int e = threadIdx.x; e < 384; e += 256){
      int zz = e / 192, qq = e % 192;
      const float* w2src = zz ? divw2 : simw2;
      float4 wv = reinterpret_cast<const float4*>(w2src)[qq];
      ushort4 o;
      o.x = f2h_bits(wv.x); o.y = f2h_bits(wv.y); o.z = f2h_bits(wv.z); o.w = f2h_bits(wv.w);
      reinterpret_cast<ushort4*>(w2h + zz*HDIM)[qq] = o;
    }
  }
}

// ---------------- gemm5v5_k: rolled loop + 4-way k-split ----------------
// grid (ntile=24, mtile=12, z=5)   [r20 bug: gridDim.x was 12 -> half of n unwritten]
// wave w owns k-quarter w (6 kchunks of 32).
struct G5M4 {
  const float* b1f[4];
  u16* outH[4];
  float* outF;
  const float* bsum;
};

__global__ __launch_bounds__(256, 2) void gemm5v5_k(const u16* __restrict__ tiles, G5M4 ga){
  __shared__ f32x4 red[3][4][64];   // waves 1..3 publish; 12KB
  int z = blockIdx.z;
  int t = threadIdx.x, lane = t&63, w = t>>6;
  int ntile = blockIdx.x, mtile = blockIdx.y;
  const u16* Ab = tiles + ((size_t)((mtile*24 + w*6)*128 + lane))*8;
  const u16* Bb = tiles + (size_t)(EMB_SLOTS + z*W_SLOTS)*8
                        + ((size_t)((ntile*24 + w*6)*128 + lane))*8;
  f32x4 acc00={0,0,0,0}, acc01={0,0,0,0}, acc10={0,0,0,0}, acc11={0,0,0,0};
  bf16x8 a0 = *reinterpret_cast<const bf16x8*>(Ab);
  bf16x8 a1 = *reinterpret_cast<const bf16x8*>(Ab + 512);
  bf16x8 b0 = *reinterpret_cast<const bf16x8*>(Bb);
  bf16x8 b1 = *reinterpret_cast<const bf16x8*>(Bb + 512);
#pragma unroll 1
  for (int c=0;c<6;c++){
    bf16x8 na0=a0, na1=a1, nb0=b0, nb1=b1;
    if (c < 5){
      na0 = *reinterpret_cast<const bf16x8*>(Ab + 1024);
      na1 = *reinterpret_cast<const bf16x8*>(Ab + 1536);
      nb0 = *reinterpret_cast<const bf16x8*>(Bb + 1024);
      nb1 = *reinterpret_cast<const bf16x8*>(Bb + 1536);
    }
    acc00 = __builtin_amdgcn_mfma_f32_16x16x32_bf16(a0, b0, acc00, 0, 0, 0);
    acc10 = __builtin_amdgcn_mfma_f32_16x16x32_bf16(a1, b0, acc10, 0, 0, 0);
    acc01 = __builtin_amdgcn_mfma_f32_16x16x32_bf16(a0, b1, acc01, 0, 0, 0);
    acc11 = __builtin_amdgcn_mfma_f32_16x16x32_bf16(a1, b1, acc11, 0, 0, 0);
    a0 = na0; a1 = na1; b0 = nb0; b1 = nb1;
    Ab += 1024; Bb += 1024;
  }
  if (w > 0){
    red[w-1][0][lane] = acc00;
    red[w-1][1][lane] = acc01;
    red[w-1][2][lane] = acc10;
    red[w-1][3][lane] = acc11;
  }
  __syncthreads();
  if (w == 0){
#pragma unroll
    for (int ww=0;ww<3;ww++){
      acc00 += red[ww][0][lane];
      acc01 += red[ww][1][lane];
      acc10 += red[ww][2][lane];
      acc11 += red[ww][3][lane];
    }
    int l15 = lane & 15;
    int r0 = (lane>>4)*4;
    int m0 = mtile*32, n0 = ntile*32;
    if (z < 4){
      u16* outp = ga.outH[z];
      if ((z & 1) == 0){
        const float* b1f = ga.b1f[z];
        float bn0 = b1f[n0 + l15];
        float bn1 = b1f[n0 + 16 + l15];
#pragma unroll
        for (int r=0;r<4;r++){
          outp[(size_t)(m0 + r0 + r)*HDIM      + n0 + l15]      = f2h_bits(acc00[r] + bn0);
          outp[(size_t)(m0 + r0 + r)*HDIM      + n0 + 16 + l15] = f2h_bits(acc01[r] + bn1);
          outp[(size_t)(m0 + 16 + r0 + r)*HDIM + n0 + l15]      = f2h_bits(acc10[r] + bn0);
          outp[(size_t)(m0 + 16 + r0 + r)*HDIM + n0 + 16 + l15] = f2h_bits(acc11[r] + bn1);
        }
      } else {
#pragma unroll
        for (int r=0;r<4;r++){
          outp[rswz(m0 + r0 + r,      n0 + l15)]      = f2h_bits(acc00[r]);
          outp[rswz(m0 + r0 + r,      n0 + 16 + l15)] = f2h_bits(acc01[r]);
          outp[rswz(m0 + 16 + r0 + r, n0 + l15)]      = f2h_bits(acc10[r]);
          outp[rswz(m0 + 16 + r0 + r, n0 + 16 + l15)] = f2h_bits(acc11[r]);
        }
      }
    } else {
      float* outp = ga.outF;
      float bn0 = ga.bsum[n0 + l15];
      float bn1 = ga.bsum[n0 + 16 + l15];
#pragma unroll
      for (int r=0;r<4;r++){
        outp[(size_t)(m0 + r0 + r)*HDIM      + n0 + l15]      = (acc00[r] + bn0)*0.125f;
        outp[(size_t)(m0 + r0 + r)*HDIM      + n0 + 16 + l15] = (acc01[r] + bn1)*0.125f;
        outp[(size_t)(m0 + 16 + r0 + r)*HDIM + n0 + l15]      = (acc10[r] + bn0)*0.125f;
        outp[(size_t)(m0 + 16 + r0 + r)*HDIM + n0 + 16 + l15] = (acc11[r] + bn1)*0.125f;
      }
    }
  }
}

// ---------------- pair6_k: rolled c-loop (r13 exact), coalesced swizzled R ----------------
struct P6Args {
  const u16* L[2];      // row-major f16 [384][768], b1 folded
  const u16* R[2];      // swizzled f16 (rswz layout)
  const u16* w2h;       // [2][768] f16
  const float* b2[2];
  float* out[2];
};

#define PDOT(LW, RW, WW, ACC) {                                               \
  h2v s_ = __builtin_elementwise_max(                                         \
      __builtin_bit_cast(h2v,(LW)) + __builtin_bit_cast(h2v,(RW)), hz);       \
  ACC = __builtin_amdgcn_fdot2(s_, __builtin_bit_cast(h2v,(WW)), ACC, false); }

__global__ __launch_bounds__(256, 2) void pair6_k(P6Args pa){
  int z = blockIdx.z;
  int i0 = blockIdx.x*8;        // 48 i-blocks
  int jt = blockIdx.y;          // 12 j-tiles (32 j)
  __shared__ u16 Lh[8][768];    // 12KB
  __shared__ u16 w2s[768];      // 1.5KB
  int t = threadIdx.x;
  const u16* __restrict__ L = pa.L[z];
  for (int idx=t; idx<1536; idx+=256){
    int ii = idx/192, qq = idx - ii*192;
    reinterpret_cast<ushort4*>(&Lh[ii][0])[qq] =
        reinterpret_cast<const ushort4*>(L + (size_t)(i0+ii)*HDIM)[qq];
  }
  for (int e=t; e<192; e+=256)
    reinterpret_cast<ushort4*>(w2s)[e] = reinterpret_cast<const ushort4*>(pa.w2h + z*HDIM)[e];
  __syncthreads();
  int w = t>>6, lane = t&63;
  int s = lane>>3, g = lane&7;
  int jb = jt*32 + w*8;
  const h2v hz = {(_Float16)0.f, (_Float16)0.f};
  float acc[8] = {0.f,0.f,0.f,0.f,0.f,0.f,0.f,0.f};

  const u16* rp  = pa.R[z] + (size_t)(jb>>3)*6144 + ((size_t)lane<<3);
  const u16* wp  = &w2s[s*96];
  const u16* lp  = &Lh[0][s*96];
  uint4 rv = *reinterpret_cast<const uint4*>(rp);
#pragma unroll 1
  for (int c=0;c<12;c++){
    uint4 nrv = rv;
    if (c < 11) nrv = *reinterpret_cast<const uint4*>(rp + 512);
    uint4 wv = *reinterpret_cast<const uint4*>(wp);
#pragma unroll
    for (int ii=0;ii<8;ii++){
      uint4 lv = *reinterpret_cast<const uint4*>(lp + ii*768);
      PDOT(lv.x, rv.x, wv.x, acc[ii]);
      PDOT(lv.y, rv.y, wv.y, acc[ii]);
      PDOT(lv.z, rv.z, wv.z, acc[ii]);
      PDOT(lv.w, rv.w, wv.w, acc[ii]);
    }
    rv = nrv; rp += 512; wp += 8; lp += 8;
  }
  float b2v = pa.b2[z][0];
  float* outp = pa.out[z];
#pragma unroll
  for (int ii=0;ii<8;ii++){
    float a = acc[ii];
    a += __shfl_xor(a, 8, 64);
    a += __shfl_xor(a, 16, 64);
    a += __shfl_xor(a, 32, 64);
    if (s == ii){
      int i = i0 + ii, j = jb + g;
      float v = a + b2v;
      if (i == j) v = 0.f;
      outp[(size_t)i*NTOT + j] = v;
    }
  }
}

// ================= fallback (proven zero-ws path) =================
__global__ __launch_bounds__(256) void prop_k(
    const float* __restrict__ sup, const float* __restrict__ qry,
    const float* __restrict__ relW, const float* __restrict__ relB,
    float* __restrict__ outp){
  __shared__ float As[16][68];
  __shared__ float Bs[16][68];
  int t = threadIdx.x;
  int m0 = blockIdx.y*64, n0 = blockIdx.x*64;
  int lm = t>>2, lk = (t&3)<<2;
  int tx = t&15, ty = t>>4;
  float acc[4][4] = {{0,0,0,0},{0,0,0,0},{0,0,0,0},{0,0,0,0}};
  const float* Aptr = emb_row(sup, qry, m0+lm) + lk;
  const float* Bptr = relW + (size_t)(n0+lm)*HDIM + lk;
  for (int k0=0;k0<HDIM;k0+=16){
    float4 av = *reinterpret_cast<const float4*>(Aptr + k0);
    float4 bs = make_float4(0.f,0.f,0.f,0.f);
#pragma unroll
    for (int r=0;r<NREL;r++){
      float4 bv = *reinterpret_cast<const float4*>(Bptr + (size_t)r*WPLANE + k0);
      bs.x += bv.x; bs.y += bv.y; bs.z += bv.z; bs.w += bv.w;
    }
    __syncthreads();
    As[lk+0][lm]=av.x; As[lk+1][lm]=av.y; As[lk+2][lm]=av.z; As[lk+3][lm]=av.w;
    Bs[lk+0][lm]=bs.x; Bs[lk+1][lm]=bs.y; Bs[lk+2][lm]=bs.z; Bs[lk+3][lm]=bs.w;
    __syncthreads();
#pragma unroll
    for (int kk=0;kk<16;kk++){
      float4 a4 = *reinterpret_cast<const float4*>(&As[kk][ty<<2]);
      float4 b4 = *reinterpret_cast<const float4*>(&Bs[kk][tx<<2]);
      float ar[4]={a4.x,a4.y,a4.z,a4.w};
      float br[4]={b4.x,b4.y,b4.z,b4.w};
#pragma unroll
      for (int i2=0;i2<4;i2++)
#pragma unroll
        for (int j2=0;j2<4;j2++)
          acc[i2][j2] = fmaf(ar[i2], br[j2], acc[i2][j2]);
    }
  }
#pragma unroll
  for (int j2=0;j2<4;j2++){
    int n = n0 + (tx<<2) + j2;
    float bias = 0.f;
#pragma unroll
    for (int r=0;r<NREL;r++) bias += relB[r*HDIM + n];
#pragma unroll
    for (int i2=0;i2<4;i2++){
      int m = m0 + (ty<<2) + i2;
      outp[(size_t)m*HDIM + n] = (acc[i2][j2] + bias) * 0.125f;
    }
  }
}

struct NWArgs {
  const float* W1[2]; const float* b1[2]; const float* w2[2]; const float* b2[2];
  float* out[2];
};

__global__ __launch_bounds__(256) void pair_nows_k(
    const float* __restrict__ sup, const float* __restrict__ qry, NWArgs na){
  int z = blockIdx.z, i0 = blockIdx.x*32, j0 = blockIdx.y*32;
  __shared__ u16 Lt[32][768];
  __shared__ float Rj[768];
  __shared__ float b1s[768];
  __shared__ float w2s[768];
  const float* __restrict__ W1 = na.W1[z];
  int t = threadIdx.x;
  for (int k=t;k<768;k+=256){ b1s[k]=na.b1[z][k]; w2s[k]=na.w2[z][k]; }
  for (int e=t; e<32*768; e+=256){
    int ii = e/768, k = e - ii*768;
    const float4* er = reinterpret_cast<const float4*>(emb_row(sup, qry, i0+ii));
    const float4* wr = reinterpret_cast<const float4*>(W1 + (size_t)k*W1LD);
    float s = 0.f;
    for (int h=0;h<192;h++){
      float4 a = er[h], b = wr[h];
      s += a.x*b.x + a.y*b.y + a.z*b.z + a.w*b.w;
    }
    Lt[ii][k] = f2b(s);
  }
  float b2v = na.b2[z][0];
  int w = t>>6, l = t&63;
  float* outp = na.out[z];
  for (int jj=0;jj<32;jj++){
    int j = j0 + jj;
    const float4* ejr = reinterpret_cast<const float4*>(emb_row(sup, qry, j));
    __syncthreads();
    for (int k=t;k<768;k+=256){
      const float4* wr = reinterpret_cast<const float4*>(W1 + (size_t)k*W1LD + HDIM);
      float s = 0.f;
      for (int h=0;h<192;h++){
        float4 a = ejr[h], b = wr[h];
        s += a.x*b.x + a.y*b.y + a.z*b.z + a.w*b.w;
      }
      Rj[k] = s;
    }
    __syncthreads();
    for (int q=0;q<8;q++){
      int ii = (w<<3) + q;
      float acc = 0.f;
#pragma unroll
      for (int u=0;u<12;u++){
        int k = l + (u<<6);
        acc = fmaf(fmaxf(b2f(Lt[ii][k]) + Rj[k] + b1s[k], 0.f), w2s[k], acc);
      }
#pragma unroll
      for (int m=32;m>=1;m>>=1) acc += __shfl_xor(acc, m, 64);
      if (l==0){
        int i = i0 + ii;
        float v = acc + b2v;
        if (i==j) v = 0.f;
        outp[(size_t)i*NTOT + j] = v;
      }
    }
  }
}

extern "C" void kernel_launch(void* const* d_in, const int* in_sizes, int n_in,
                              void* d_out, int out_size, void* d_ws, size_t ws_size,
                              hipStream_t stream) {
  const float* sup   = (const float*)d_in[0];
  // d_in[1] = support_labels (unused)
  const float* qry   = (const float*)d_in[2];
  const float* simW1 = (const float*)d_in[3];
  const float* simb1 = (const float*)d_in[4];
  const float* simw2 = (const float*)d_in[5];
  const float* simb2 = (const float*)d_in[6];
  const float* divW1 = (const float*)d_in[7];
  const float* divb1 = (const float*)d_in[8];
  const float* divw2 = (const float*)d_in[9];
  const float* divb2 = (const float*)d_in[10];
  const float* relW  = (const float*)d_in[11];
  const float* relB  = (const float*)d_in[12];
  float* out = (float*)d_out;
  float* outSim = out + (size_t)NTOT*HDIM;
  float* outDiv = outSim + (size_t)NTOT*NTOT;

  const size_t TILB = (size_t)TILES_SLOTS*8*2;   // 6,488,064 B
  const size_t LRB  = (size_t)NTOT*HDIM*2;       //   589,824 B
  const size_t NEED = TILB + 8192 + 4*LRB;       // ~8.86 MB

  if (ws_size >= NEED){
    char* ws = (char*)d_ws;
    u16*   tiles = (u16*)(ws);
    float* bsum  = (float*)(ws + TILB);
    u16*   w2h   = (u16*)(ws + TILB + 4096);
    u16*   Ls    = (u16*)(ws + TILB + 8192);
    u16*   Rs    = (u16*)((char*)Ls + LRB);
    u16*   Ld    = (u16*)((char*)Rs + LRB);
    u16*   Rd    = (u16*)((char*)Ld + LRB);

    prep2_k<<<dim3((TILES_SLOTS + 255)/256), dim3(256), 0, stream>>>(
        sup, qry, relW, relB, simW1, divW1, simw2, divw2, tiles, bsum, w2h);

    G5M4 ga;
    ga.b1f[0]=simb1;   ga.outH[0]=Ls;
    ga.b1f[1]=nullptr; ga.outH[1]=Rs;
    ga.b1f[2]=divb1;   ga.outH[2]=Ld;
    ga.b1f[3]=nullptr; ga.outH[3]=Rd;
    ga.outF=out; ga.bsum=bsum;
    // r20 bug fix: ntile spans 24 tiles (768 cols), not 12.
    gemm5v5_k<<<dim3(24,12,5), dim3(256), 0, stream>>>(tiles, ga);

    P6Args pa;
    pa.L[0]=Ls; pa.R[0]=Rs; pa.b2[0]=simb2; pa.out[0]=outSim;
    pa.L[1]=Ld; pa.R[1]=Rd; pa.b2[1]=divb2; pa.out[1]=outDiv;
    pa.w2h = w2h;
    pair6_k<<<dim3(48,12,2), dim3(256), 0, stream>>>(pa);
  } else {
    prop_k<<<dim3(12,6), dim3(256), 0, stream>>>(sup, qry, relW, relB, out);
    NWArgs na;
    na.W1[0]=simW1; na.b1[0]=simb1; na.w2[0]=simw2; na.b2[0]=simb2; na.out[0]=outSim;
    na.W1[1]=divW1; na.b1[1]=divb1; na.w2[1]=divw2; na.b2[1]=divb2; na.out[1]=outDiv;
    pair_nows_k<<<dim3(12,12,2), dim3(256), 0, stream>>>(sup, qry, na);
  }
}